// Round 12
// baseline (101.111 us; speedup 1.0000x reference)
//
#include <hip/hip_runtime.h>

// Attention 8192x8192, D=DV=64, fp32 in/out.
// R12: K tiles staged to LDS via global_load_lds DMA (no VGPR cost) ->
// per-wave state fits 128 regs -> 1024-thread blocks, 4 waves/SIMD (2x R10).
// 16 waves = 2 row-halves x 8 key-chunks, 256-key tiles double-buffered in
// LDS, one barrier/iter (DMA issued at top, drained at bottom). V direct to
// registers one iteration ahead (wave-pair L1 sharing). Two-stage
// QKEXP(t)||PV(t-1) pipeline with P-parity regions. Fixed-offset softmax,
// fragment-linear bf16 K/Vt prepass, (O,l) partials + merge kernel.

#define NQ 8192
#define NK 8192

typedef float f32x4 __attribute__((ext_vector_type(4)));
typedef short short8 __attribute__((ext_vector_type(8)));
union U4 { uint4 u; short8 s; };

#define MFMA16 __builtin_amdgcn_mfma_f32_16x16x32_bf16

// round-to-nearest-even fp32->bf16 pair pack (lo = a) — prepass/Q only
__device__ __forceinline__ unsigned pk2(float a, float b) {
    unsigned ua = __builtin_bit_cast(unsigned, a);
    unsigned ub = __builtin_bit_cast(unsigned, b);
    ua = (ua + 0x7FFFu + ((ua >> 16) & 1u)) >> 16;
    ub = (ub + 0x7FFFu + ((ub >> 16) & 1u)) & 0xFFFF0000u;
    return ua | ub;
}

// 1-op truncation pack: dst = {hi16(b), hi16(a)} (lo = a)
__device__ __forceinline__ unsigned pkt(float a, float b) {
    return __builtin_amdgcn_perm(__builtin_bit_cast(unsigned, b),
                                 __builtin_bit_cast(unsigned, a), 0x07060302u);
}

// async 16B/lane global->LDS: per-lane global addr, wave-uniform LDS base,
// data lands at ldsbase + lane*16 (m97/m104 semantics).
__device__ __forceinline__ void async16(const uint4* g, uint4* l) {
    __builtin_amdgcn_global_load_lds(
        (const __attribute__((address_space(1))) void*)g,
        (__attribute__((address_space(3))) void*)l, 16, 0, 0);
}

// ---- prepass: swizzle K/V into fragment-linear bf16 layouts ----
__global__ __launch_bounds__(256)
void prepass(const float* __restrict__ Kg, const float* __restrict__ Vg,
             uint4* __restrict__ Kb4, uint4* __restrict__ Vt4) {
    __shared__ float ld[64 * 33];
    const int t = threadIdx.x, b = blockIdx.x;

    if (b < 256) {
        const int kl = t >> 3, dg = t & 7;
        const int e = kl & 1, i16 = kl >> 1, h = dg >> 2, q = dg & 3;
        const float* gp = Kg + (size_t)(b * 32 + kl) * 64 + dg * 8;
        float4 f0 = *(const float4*)gp;
        float4 f1 = *(const float4*)(gp + 4);
        uint4 o = make_uint4(pk2(f0.x, f0.y), pk2(f0.z, f0.w),
                             pk2(f1.x, f1.y), pk2(f1.z, f1.w));
        Kb4[(size_t)(b * 4 + e * 2 + h) * 64 + i16 * 4 + q] = o;
    } else {
        const int c = b - 256;
        {
            const int key = t >> 3, dg = t & 7;
            const float* gp = Vg + (size_t)(c * 32 + key) * 64 + dg * 8;
            float4 f0 = *(const float4*)gp;
            float4 f1 = *(const float4*)(gp + 4);
            ld[(dg * 8 + 0) * 33 + key] = f0.x;
            ld[(dg * 8 + 1) * 33 + key] = f0.y;
            ld[(dg * 8 + 2) * 33 + key] = f0.z;
            ld[(dg * 8 + 3) * 33 + key] = f0.w;
            ld[(dg * 8 + 4) * 33 + key] = f1.x;
            ld[(dg * 8 + 5) * 33 + key] = f1.y;
            ld[(dg * 8 + 6) * 33 + key] = f1.z;
            ld[(dg * 8 + 7) * 33 + key] = f1.w;
        }
        __syncthreads();
        {
            const int dim = t >> 2, kq = t & 3;
            const int dt = dim >> 4, i16 = dim & 15;
            float v[8];
            #pragma unroll
            for (int j = 0; j < 8; ++j) v[j] = ld[dim * 33 + kq * 8 + j];
            uint4 o = make_uint4(pk2(v[0], v[1]), pk2(v[2], v[3]),
                                 pk2(v[4], v[5]), pk2(v[6], v[7]));
            Vt4[(size_t)(c * 4 + dt) * 64 + i16 * 4 + kq] = o;
        }
    }
}

// ---- main kernel: 64 rows x 4096 keys per block, writes (O,l) partials ----
__global__ __launch_bounds__(1024)
void attn_main(const float* __restrict__ Qg,
               const uint4* __restrict__ Kb4,
               const uint4* __restrict__ Vt4,
               float* __restrict__ Opart,
               float* __restrict__ Lpart) {
    // LDS (uint4 units): [0,2048) Ktile buf0, [2048,4096) Ktile buf1,
    // [4096,8192) P regions [(w*2+rt)*2+par] x 64. 128 KB total.
    // Merge phase aliases 8 regions x 2080 floats (66,560 B) from offset 0.
    __shared__ uint4 shb4[8192];
    float* sF = (float*)shb4;
    unsigned* shu = (unsigned*)shb4;

    const int t = threadIdx.x, w = t >> 6, lane = t & 63;
    const int q = lane >> 4, i16 = lane & 15;
    const int rh = w >> 3;           // row-half 0/1
    const int kc = w & 7;            // key-chunk within tile
    const int bid = blockIdx.x;
    const int kh = bid & 1;          // key half 0/1
    const int rg = bid >> 1;         // row group 0..127
    const int qb0 = rg * 64;
    const int lsl = i16 * 4 + q;     // lane-linear slot (0..63)
    const int phase = rg & 15;       // tile-order rotation (16 tiles)

    // Q fragments: 2 row-tiles for this wave's row-half (scale 1/8*log2e)
    const float SCL = 0.18033688011112042f;
    short8 aq[2][2];
    #pragma unroll
    for (int rt = 0; rt < 2; ++rt) {
        const float* qp = Qg + (size_t)(qb0 + rh * 32 + rt * 16 + i16) * 64 + q * 8;
        float4 f0 = *(const float4*)(qp);
        float4 f1 = *(const float4*)(qp + 4);
        U4 u;
        u.u = make_uint4(pk2(f0.x * SCL, f0.y * SCL), pk2(f0.z * SCL, f0.w * SCL),
                         pk2(f1.x * SCL, f1.y * SCL), pk2(f1.z * SCL, f1.w * SCL));
        aq[rt][0] = u.s;
        f0 = *(const float4*)(qp + 32);
        f1 = *(const float4*)(qp + 36);
        u.u = make_uint4(pk2(f0.x * SCL, f0.y * SCL), pk2(f0.z * SCL, f0.w * SCL),
                         pk2(f1.x * SCL, f1.y * SCL), pk2(f1.z * SCL, f1.w * SCL));
        aq[rt][1] = u.s;
    }

    f32x4 acc[2][4];           // O partial accumulators (AGPR), static idx
    float lsum[2][4];          // per-lane row-sum partials (VALU)
    #pragma unroll
    for (int rt = 0; rt < 2; ++rt) {
        #pragma unroll
        for (int dt = 0; dt < 4; ++dt) { acc[rt][dt][0]=0.f; acc[rt][dt][1]=0.f; acc[rt][dt][2]=0.f; acc[rt][dt][3]=0.f; }
        #pragma unroll
        for (int r = 0; r < 4; ++r) lsum[rt][r] = 0.f;
    }

    // P slot indices (layout verified in R2-R11)
    const int tpw = ((i16 >> 2) & 1) + 2 * q + 32 * (i16 >> 3);  // tp = tpw + 8r
    const int pp  = i16 & 3;
    const int tpr = (q & 1) + 2 * ((i16 >> 2) & 3) + 8 * (i16 & 3) + 32 * (q >> 1);

    uint4 vf[4];               // V fragments for tile t (consumed at t+1)

    // DMA this wave's 2 K-segments of tile TT into LDS buffer B.
    // Tile = 8 chunks x 256 uint4; wave w covers uint4 [w*128, w*128+128).
#define DMA_K(TT, B)                                                          \
    do {                                                                      \
        const int Tp = ((TT) + phase) & 15;                                   \
        _Pragma("unroll")                                                     \
        for (int i = 0; i < 2; ++i) {                                         \
            const int o = w * 128 + i * 64;                                   \
            const int cg = (kh << 7) + Tp * 8 + (o >> 8);                     \
            async16(Kb4 + (size_t)(cg * 4 + ((o >> 6) & 3)) * 64 + lane,      \
                    shb4 + (B) * 2048 + o);                                   \
        }                                                                     \
    } while (0)

    // V fragments for tile TT (direct from L2; wave-pair shares -> L1 hit)
#define LOADV(TT)                                                             \
    do {                                                                      \
        const int Tp = ((TT) + phase) & 15;                                   \
        const int cg = (kh << 7) + Tp * 8 + kc;                               \
        _Pragma("unroll")                                                     \
        for (int dt = 0; dt < 4; ++dt)                                        \
            vf[dt] = Vt4[(size_t)(cg * 4 + dt) * 64 + lsl];                   \
    } while (0)

    // stage 1: QK^T from LDS K-tile buffer B -> exp2 -> pack P into parity PAR
#define QKEXP(B, PAR)                                                         \
    do {                                                                      \
        const uint4* kbuf = shb4 + (B) * 2048 + kc * 256;                     \
        U4 u0, u1, u2, u3;                                                    \
        u0.u = kbuf[0 * 64 + lsl];                                            \
        u1.u = kbuf[1 * 64 + lsl];                                            \
        u2.u = kbuf[2 * 64 + lsl];                                            \
        u3.u = kbuf[3 * 64 + lsl];                                            \
        _Pragma("unroll")                                                     \
        for (int rt = 0; rt < 2; ++rt) {                                      \
            f32x4 s0, s1;                                                     \
            s0[0]=-16.f; s0[1]=-16.f; s0[2]=-16.f; s0[3]=-16.f;               \
            s1[0]=-16.f; s1[1]=-16.f; s1[2]=-16.f; s1[3]=-16.f;               \
            s0 = MFMA16(aq[rt][0], u0.s, s0, 0, 0, 0);                        \
            s0 = MFMA16(aq[rt][1], u1.s, s0, 0, 0, 0);                        \
            s1 = MFMA16(aq[rt][0], u2.s, s1, 0, 0, 0);                        \
            s1 = MFMA16(aq[rt][1], u3.s, s1, 0, 0, 0);                        \
            const int rbase = (4096 + (((w * 2 + rt) * 2) + (PAR)) * 64) * 4; \
            _Pragma("unroll")                                                 \
            for (int r = 0; r < 4; ++r) {                                     \
                float p0 = __builtin_amdgcn_exp2f(s0[r]);                     \
                float p1 = __builtin_amdgcn_exp2f(s1[r]);                     \
                lsum[rt][r] += p0;                                            \
                lsum[rt][r] += p1;                                            \
                shu[rbase + (tpw + 8 * r) * 4 + pp] = pkt(p0, p1);            \
            }                                                                 \
        }                                                                     \
    } while (0)

    // stage 2: P A-frags from parity PAR, PV MFMA with vf
#define PVS(PAR)                                                              \
    do {                                                                      \
        U4 ap0, ap1;                                                          \
        ap0.u = shb4[4096 + (((w * 2 + 0) * 2) + (PAR)) * 64 + tpr];          \
        ap1.u = shb4[4096 + (((w * 2 + 1) * 2) + (PAR)) * 64 + tpr];          \
        _Pragma("unroll")                                                     \
        for (int dt = 0; dt < 4; ++dt) {                                      \
            U4 bv; bv.u = vf[dt];                                             \
            acc[0][dt] = MFMA16(ap0.s, bv.s, acc[0][dt], 0, 0, 0);            \
            acc[1][dt] = MFMA16(ap1.s, bv.s, acc[1][dt], 0, 0, 0);            \
        }                                                                     \
    } while (0)

    // ---- pipelined main loop ----
    DMA_K(0, 0);
    __syncthreads();          // tile 0 staged
    // t = 0
    DMA_K(1, 1);
    QKEXP(0, 0);
    LOADV(0);
    __syncthreads();
    #pragma unroll 1
    for (int tt = 1; tt < 15; tt += 2) {
        // t = tt (odd): K from buf1, P par1, PV(t-1) par0 with vf=V(t-1)
        DMA_K(tt + 1, 0);
        QKEXP(1, 1);
        PVS(0);
        LOADV(tt);
        __syncthreads();
        // t = tt+1 (even): K from buf0, P par0, PV par1
        DMA_K(tt + 2, 1);
        QKEXP(0, 0);
        PVS(1);
        LOADV(tt + 1);
        __syncthreads();
    }
    // t = 15 (odd): K from buf1
    QKEXP(1, 1);
    PVS(0);                   // uses V(14)
    LOADV(15);
    PVS(1);                   // uses V(15); vmcnt wait once

    // ---- reduce row-sum partials across the 16 key-lanes of each quad ----
    #pragma unroll
    for (int rt = 0; rt < 2; ++rt)
        #pragma unroll
        for (int r = 0; r < 4; ++r) {
            float v = lsum[rt][r];
            v += __shfl_xor(v, 1);
            v += __shfl_xor(v, 2);
            v += __shfl_xor(v, 4);
            v += __shfl_xor(v, 8);
            lsum[rt][r] = v;   // uniform across the 16 lanes of quad q
        }

    // ---- tree-merge the 8 key-chunk partials within each row-half ----
    __syncthreads();
    #pragma unroll 1
    for (int step = 4; step >= 1; step >>= 1) {
        if (kc >= step && kc < 2 * step) {
            float* base = sF + (rh * 4 + (kc - step)) * 2080;
            #pragma unroll
            for (int rt = 0; rt < 2; ++rt) {
                #pragma unroll
                for (int dt = 0; dt < 4; ++dt)
                    #pragma unroll
                    for (int r = 0; r < 4; ++r)
                        base[(rt * 16 + 4 * q + r) * 64 + dt * 16 + i16] = acc[rt][dt][r];
                if (i16 == 0) {
                    #pragma unroll
                    for (int r = 0; r < 4; ++r) base[2048 + rt * 16 + 4 * q + r] = lsum[rt][r];
                }
            }
        }
        __syncthreads();
        if (kc < step) {
            const float* base = sF + (rh * 4 + kc) * 2080;
            #pragma unroll
            for (int rt = 0; rt < 2; ++rt) {
                #pragma unroll
                for (int dt = 0; dt < 4; ++dt)
                    #pragma unroll
                    for (int r = 0; r < 4; ++r)
                        acc[rt][dt][r] += base[(rt * 16 + 4 * q + r) * 64 + dt * 16 + i16];
                #pragma unroll
                for (int r = 0; r < 4; ++r) lsum[rt][r] += base[2048 + rt * 16 + 4 * q + r];
            }
        }
        __syncthreads();
    }

    // ---- kc==0 waves (w=0, w=8) write their row-half's (O,l) partial ----
    if (kc == 0) {
        #pragma unroll
        for (int rt = 0; rt < 2; ++rt) {
            #pragma unroll
            for (int dt = 0; dt < 4; ++dt)
                #pragma unroll
                for (int r = 0; r < 4; ++r) {
                    const int row = qb0 + rh * 32 + rt * 16 + 4 * q + r;
                    Opart[((size_t)kh * 8192 + row) * 64 + dt * 16 + i16] = acc[rt][dt][r];
                }
            if (i16 == 0) {
                #pragma unroll
                for (int r = 0; r < 4; ++r)
                    Lpart[kh * 8192 + qb0 + rh * 32 + rt * 16 + 4 * q + r] = lsum[rt][r];
            }
        }
    }
}

// ---- merge: O = (O0 + O1) / (l0 + l1) ----
__global__ __launch_bounds__(256)
void merge(const float* __restrict__ Opart, const float* __restrict__ Lpart,
           float* __restrict__ Og) {
    const int idx = blockIdx.x * 256 + threadIdx.x;   // 0..131071
    const int row = idx >> 4, seg = idx & 15;
    const float4 a = *(const float4*)(Opart + (size_t)row * 64 + seg * 4);
    const float4 b = *(const float4*)(Opart + ((size_t)8192 + row) * 64 + seg * 4);
    const float inv = 1.0f / (Lpart[row] + Lpart[8192 + row]);
    float4 o;
    o.x = (a.x + b.x) * inv;
    o.y = (a.y + b.y) * inv;
    o.z = (a.z + b.z) * inv;
    o.w = (a.w + b.w) * inv;
    *(float4*)(Og + (size_t)row * 64 + seg * 4) = o;
}

extern "C" void kernel_launch(void* const* d_in, const int* in_sizes, int n_in,
                              void* d_out, int out_size, void* d_ws, size_t ws_size,
                              hipStream_t stream) {
    const float* Q = (const float*)d_in[0];
    const float* K = (const float*)d_in[1];
    const float* V = (const float*)d_in[2];
    float* O = (float*)d_out;
    char* ws = (char*)d_ws;
    uint4* Kb4   = (uint4*)ws;                        // 1 MB, fragment-linear
    uint4* Vt4   = (uint4*)(ws + (1 << 20));          // 1 MB, fragment-linear
    float* Opart = (float*)(ws + (2 << 20));          // 2 x 8192 x 64 fp32 = 4 MB
    float* Lpart = (float*)(ws + (6 << 20));          // 2 x 8192 fp32
    hipLaunchKernelGGL(prepass, dim3(512), dim3(256), 0, stream, K, V, Kb4, Vt4);
    hipLaunchKernelGGL(attn_main, dim3(256), dim3(1024), 0, stream, Q, Kb4, Vt4, Opart, Lpart);
    hipLaunchKernelGGL(merge, dim3(512), dim3(256), 0, stream, Opart, Lpart, O);
}